// Round 1
// baseline (807.304 us; speedup 1.0000x reference)
//
#include <hip/hip_runtime.h>
#include <math.h>

// Problem constants
#define BB 2
#define CC 512
#define DD 512
#define HH 8
#define DH 64
#define TI 8     // i-rows per block in attn_main
#define TJ 64    // j-tile

// workspace layout: 6 segments of B*H*C*DH floats = 6 * 524288 * 4B = 12.6 MB
// (q, k, v, hqc=b1+q@W1q, hk=k@W1k, attn_out)

__device__ __forceinline__ float fast_rcp(float x) {
#if __has_builtin(__builtin_amdgcn_rcpf)
    return __builtin_amdgcn_rcpf(x);
#else
    return 1.0f / x;
#endif
}

// exact-erf gelu via Abramowitz-Stegun 7.1.26 (|eps| <= 1.5e-7)
__device__ __forceinline__ float gelu_exact(float h) {
    float u = h * 0.70710678118654752f;
    float a = fabsf(u);
    float t = fast_rcp(1.0f + 0.3275911f * a);
    float poly = t * (0.254829592f + t * (-0.284496736f + t * (1.421413741f +
                 t * (-1.453152027f + t * 1.061405429f))));
    float ex = __expf(-a * a);
    float erfa = 1.0f - poly * ex;
    float erfu = copysignf(erfa, u);
    return 0.5f * h * (1.0f + erfu);
}

// ---------------------------------------------------------------------------
// Kernel A: q,k,v = x @ {Wq,Wk,Wv} + bias, output layout [b][h][c][e]
// M=1024 rows (b*C+c), 3 x N=512, K=512. 64x64 block tile, 4x4 per thread.
// ---------------------------------------------------------------------------
__global__ __launch_bounds__(256) void qkv_gemm(
    const float* __restrict__ x,
    const float* __restrict__ Wq, const float* __restrict__ bq,
    const float* __restrict__ Wk, const float* __restrict__ bk,
    const float* __restrict__ Wv, const float* __restrict__ bv,
    float* __restrict__ qw, float* __restrict__ kw, float* __restrict__ vw)
{
    __shared__ float As[16][68];   // [kk][m]
    __shared__ float Bs[16][68];   // [kk][n]
    int t = threadIdx.x;
    int m0 = blockIdx.x * 64;
    int by = blockIdx.y;           // 0..23
    int mat = by >> 3;             // 0:q 1:k 2:v
    int n0 = (by & 7) * 64;        // within-matrix col base
    const float* W    = (mat == 0) ? Wq : (mat == 1) ? Wk : Wv;
    const float* bias = (mat == 0) ? bq : (mat == 1) ? bk : bv;
    float* out        = (mat == 0) ? qw : (mat == 1) ? kw : vw;

    int tm = t & 15, tn = t >> 4;
    int lm = t >> 2;              // staging row 0..63
    int lk4 = (t & 3) * 4;        // staging k offset
    float acc[4][4] = {};

    for (int k0 = 0; k0 < 512; k0 += 16) {
        float4 av  = *(const float4*)&x[(m0 + lm) * 512 + k0 + lk4];
        float4 bv4 = *(const float4*)&W[(k0 + (t >> 4)) * 512 + n0 + (t & 15) * 4];
        As[lk4 + 0][lm] = av.x; As[lk4 + 1][lm] = av.y;
        As[lk4 + 2][lm] = av.z; As[lk4 + 3][lm] = av.w;
        *(float4*)&Bs[t >> 4][(t & 15) * 4] = bv4;
        __syncthreads();
        #pragma unroll
        for (int kk = 0; kk < 16; ++kk) {
            float4 a4 = *(float4*)&As[kk][tm * 4];
            float4 b4 = *(float4*)&Bs[kk][tn * 4];
            float aa[4] = {a4.x, a4.y, a4.z, a4.w};
            float bb[4] = {b4.x, b4.y, b4.z, b4.w};
            #pragma unroll
            for (int r = 0; r < 4; ++r)
                #pragma unroll
                for (int c = 0; c < 4; ++c)
                    acc[r][c] += aa[r] * bb[c];
        }
        __syncthreads();
    }
    int h = n0 >> 6;               // whole 64-tile lies in one head
    int e0 = tn * 4;
    float4 bb4 = *(const float4*)&bias[n0 + e0];
    float badd[4] = {bb4.x, bb4.y, bb4.z, bb4.w};
    #pragma unroll
    for (int rr = 0; rr < 4; ++rr) {
        int r = m0 + tm * 4 + rr;
        int b = r >> 9, c = r & 511;
        float4 o;
        o.x = acc[rr][0] + badd[0];
        o.y = acc[rr][1] + badd[1];
        o.z = acc[rr][2] + badd[2];
        o.w = acc[rr][3] + badd[3];
        *(float4*)&out[((b * HH + h) * CC + c) * DH + e0] = o;
    }
}

// ---------------------------------------------------------------------------
// Kernel A2: hqc = b1 + q @ W1[0:64]   (z=0)
//            hk  =      k @ W1[64:128] (z=1)
// rows = B*H*C = 8192 flat; 64 rows per block.
// ---------------------------------------------------------------------------
__global__ __launch_bounds__(256) void h_lin(
    const float* __restrict__ q, const float* __restrict__ k,
    const float* __restrict__ W1, const float* __restrict__ b1,
    float* __restrict__ hqc, float* __restrict__ hkw)
{
    int z = blockIdx.y;
    const float* src = (z == 0) ? q : k;
    float* dst = (z == 0) ? hqc : hkw;
    __shared__ float ws[64][68];   // W1z[d][e]
    __shared__ float rsT[64][68];  // src transposed [d][row]
    int t = threadIdx.x;
    int r0 = blockIdx.x * 64;

    for (int idx = t; idx < 4096; idx += 256) {
        int d = idx >> 6, e = idx & 63;
        ws[d][e] = W1[(z * 64 + d) * 64 + e];
    }
    {
        int j = t >> 2;
        int d0 = (t & 3) * 16;
        #pragma unroll
        for (int c = 0; c < 16; c += 4) {
            float4 vv = *(const float4*)&src[(r0 + j) * 64 + d0 + c];
            rsT[d0 + c + 0][j] = vv.x; rsT[d0 + c + 1][j] = vv.y;
            rsT[d0 + c + 2][j] = vv.z; rsT[d0 + c + 3][j] = vv.w;
        }
    }
    __syncthreads();
    int j = t & 63;
    int e0 = (t >> 6) * 16;
    float acc[16] = {};
    for (int d = 0; d < 64; ++d) {
        float kv = rsT[d][j];
        #pragma unroll
        for (int c = 0; c < 16; ++c) acc[c] += kv * ws[d][e0 + c];
    }
    if (z == 0) {
        #pragma unroll
        for (int c = 0; c < 16; ++c) acc[c] += b1[e0 + c];
    }
    #pragma unroll
    for (int c = 0; c < 16; c += 4) {
        float4 o = {acc[c], acc[c + 1], acc[c + 2], acc[c + 3]};
        *(float4*)&dst[(r0 + j) * 64 + e0 + c] = o;
    }
}

// ---------------------------------------------------------------------------
// Kernel B: the second-order attention core.
// Block = (b,h) x 8 i-rows. h[i,j,e] = cs[i][e] + hk[j][e] + sum_d qk[d]*W1i[d][e]
// scores -> softmax -> out = attn @ v
// ---------------------------------------------------------------------------
__global__ __launch_bounds__(256) void attn_main(
    const float* __restrict__ qw, const float* __restrict__ kw,
    const float* __restrict__ vw,
    const float* __restrict__ hqc, const float* __restrict__ hkw,
    const float* __restrict__ W1, const float* __restrict__ W2,
    const float* __restrict__ b2p,
    float* __restrict__ ow)
{
    __shared__ float w1s[64][68];   // W1i [d][e]
    __shared__ float kT[64][68];    // [d][j] current j-tile
    __shared__ float hks[64][68];   // [j][e] current j-tile
    __shared__ float qs[TI][64];
    __shared__ float cs[TI][64];
    __shared__ float sc[TI][512];
    __shared__ float w2s[64];

    int t = threadIdx.x;
    int bh = blockIdx.x >> 6;             // 0..15
    int i0 = (blockIdx.x & 63) * TI;
    const float* qb  = qw  + ((size_t)bh * CC + i0) * DH;
    const float* kb  = kw  + (size_t)bh * CC * DH;
    const float* vb  = vw  + (size_t)bh * CC * DH;
    const float* cb  = hqc + ((size_t)bh * CC + i0) * DH;
    const float* hkb = hkw + (size_t)bh * CC * DH;

    for (int idx = t; idx < 4096; idx += 256) {
        int d = idx >> 6, e = idx & 63;
        w1s[d][e] = W1[(128 + d) * 64 + e];
    }
    for (int idx = t; idx < TI * 64; idx += 256) {
        int i = idx >> 6, d = idx & 63;
        qs[i][d] = qb[i * 64 + d];
        cs[i][d] = cb[i * 64 + d];
    }
    if (t < 64) w2s[t] = W2[t];
    __syncthreads();

    int eg = t & 15, jg = t >> 4;   // e-group 0..15, j-group 0..15
    int e0 = eg * 4, jj0 = jg * 4;

    for (int jt = 0; jt < 8; ++jt) {
        int j0 = jt * TJ;
        // stage kT (transposed) and hks (direct)
        {
            int j = t >> 2;
            int d0 = (t & 3) * 16;
            #pragma unroll
            for (int c = 0; c < 16; c += 4) {
                float4 vv = *(const float4*)&kb[(j0 + j) * 64 + d0 + c];
                kT[d0 + c + 0][j] = vv.x; kT[d0 + c + 1][j] = vv.y;
                kT[d0 + c + 2][j] = vv.z; kT[d0 + c + 3][j] = vv.w;
                float4 hv = *(const float4*)&hkb[(j0 + j) * 64 + d0 + c];
                *(float4*)&hks[j][d0 + c] = hv;
            }
        }
        __syncthreads();
        for (int i = 0; i < TI; ++i) {
            float acc[4][4];
            {
                float4 cv = *(float4*)&cs[i][e0];
                float ca[4] = {cv.x, cv.y, cv.z, cv.w};
                #pragma unroll
                for (int jj = 0; jj < 4; ++jj) {
                    float4 hv = *(float4*)&hks[jj0 + jj][e0];
                    acc[jj][0] = ca[0] + hv.x;
                    acc[jj][1] = ca[1] + hv.y;
                    acc[jj][2] = ca[2] + hv.z;
                    acc[jj][3] = ca[3] + hv.w;
                }
            }
            for (int d4 = 0; d4 < 64; d4 += 4) {
                float4 q4 = *(float4*)&qs[i][d4];
                float qarr[4] = {q4.x, q4.y, q4.z, q4.w};
                #pragma unroll
                for (int dd = 0; dd < 4; ++dd) {
                    float qd = qarr[dd];
                    float4 kv4 = *(float4*)&kT[d4 + dd][jj0];
                    float4 wv4 = *(float4*)&w1s[d4 + dd][e0];
                    float ka[4] = {kv4.x, kv4.y, kv4.z, kv4.w};
                    float wa[4] = {wv4.x, wv4.y, wv4.z, wv4.w};
                    float qk[4];
                    #pragma unroll
                    for (int jj = 0; jj < 4; ++jj) qk[jj] = qd * ka[jj];
                    #pragma unroll
                    for (int jj = 0; jj < 4; ++jj)
                        #pragma unroll
                        for (int ee = 0; ee < 4; ++ee)
                            acc[jj][ee] += qk[jj] * wa[ee];
                }
            }
            // gelu + dot with W2 over this thread's 4 e's
            float4 w2v = *(float4*)&w2s[e0];
            float w2a[4] = {w2v.x, w2v.y, w2v.z, w2v.w};
            float part[4];
            #pragma unroll
            for (int jj = 0; jj < 4; ++jj) {
                float p = 0.0f;
                #pragma unroll
                for (int ee = 0; ee < 4; ++ee)
                    p += gelu_exact(acc[jj][ee]) * w2a[ee];
                part[jj] = p;
            }
            // reduce over the 16 lanes sharing this j-group (lanes are
            // consecutive 16 within the wave: eg = lane & 15)
            #pragma unroll
            for (int jj = 0; jj < 4; ++jj) {
                float p = part[jj];
                p += __shfl_xor(p, 1);
                p += __shfl_xor(p, 2);
                p += __shfl_xor(p, 4);
                p += __shfl_xor(p, 8);
                part[jj] = p;
            }
            if (eg == 0) {
                sc[i][j0 + jj0 + 0] = part[0];
                sc[i][j0 + jj0 + 1] = part[1];
                sc[i][j0 + jj0 + 2] = part[2];
                sc[i][j0 + jj0 + 3] = part[3];
            }
        }
        __syncthreads();
    }

    // softmax over j per i-row; scores = (raw + b2) / 8
    float b2v = b2p[0];
    {
        int wv_ = t >> 6;
        int lane = t & 63;
        for (int ii = wv_; ii < TI; ii += 4) {
            float xv[8];
            float m = -1e30f;
            #pragma unroll
            for (int c = 0; c < 8; ++c) {
                xv[c] = (sc[ii][c * 64 + lane] + b2v) * 0.125f;
                m = fmaxf(m, xv[c]);
            }
            #pragma unroll
            for (int o = 1; o < 64; o <<= 1) m = fmaxf(m, __shfl_xor(m, o));
            float s = 0.0f;
            #pragma unroll
            for (int c = 0; c < 8; ++c) { xv[c] = __expf(xv[c] - m); s += xv[c]; }
            #pragma unroll
            for (int o = 1; o < 64; o <<= 1) s += __shfl_xor(s, o);
            float r = fast_rcp(s);
            #pragma unroll
            for (int c = 0; c < 8; ++c) sc[ii][c * 64 + lane] = xv[c] * r;
        }
    }
    __syncthreads();

    // out[i][e] = sum_j attn[i][j] * v[j][e]; thread handles 2 i's, one e
    {
        int e = t & 63;
        int g = t >> 6;
        int ia = 2 * g, ib = 2 * g + 1;
        float a0 = 0.0f, a1 = 0.0f;
        #pragma unroll 8
        for (int j = 0; j < 512; ++j) {
            float vv = vb[j * 64 + e];
            a0 += sc[ia][j] * vv;
            a1 += sc[ib][j] * vv;
        }
        ow[((size_t)bh * CC + i0 + ia) * DH + e] = a0;
        ow[((size_t)bh * CC + i0 + ib) * DH + e] = a1;
    }
}

// ---------------------------------------------------------------------------
// Kernel D: y = reshape(attn_out to (B*C, D)) @ Wo + bo
// A[r][k] = ow[((b*H + k/64)*C + c)*64 + k%64], r = b*C+c
// ---------------------------------------------------------------------------
__global__ __launch_bounds__(256) void out_gemm(
    const float* __restrict__ ow, const float* __restrict__ Wo,
    const float* __restrict__ bo, float* __restrict__ y)
{
    __shared__ float As[16][68];
    __shared__ float Bs[16][68];
    int t = threadIdx.x;
    int m0 = blockIdx.x * 64;
    int n0 = blockIdx.y * 64;
    int tm = t & 15, tn = t >> 4;
    int lm = t >> 2;
    int lk4 = (t & 3) * 4;
    float acc[4][4] = {};

    for (int k0 = 0; k0 < 512; k0 += 16) {
        int r = m0 + lm;
        int b = r >> 9, c = r & 511;
        int kk = k0 + lk4;
        int h = kk >> 6, e = kk & 63;
        float4 av  = *(const float4*)&ow[((b * HH + h) * CC + c) * DH + e];
        float4 bv4 = *(const float4*)&Wo[(k0 + (t >> 4)) * 512 + n0 + (t & 15) * 4];
        As[lk4 + 0][lm] = av.x; As[lk4 + 1][lm] = av.y;
        As[lk4 + 2][lm] = av.z; As[lk4 + 3][lm] = av.w;
        *(float4*)&Bs[t >> 4][(t & 15) * 4] = bv4;
        __syncthreads();
        #pragma unroll
        for (int kk2 = 0; kk2 < 16; ++kk2) {
            float4 a4 = *(float4*)&As[kk2][tm * 4];
            float4 b4 = *(float4*)&Bs[kk2][tn * 4];
            float aa[4] = {a4.x, a4.y, a4.z, a4.w};
            float bb[4] = {b4.x, b4.y, b4.z, b4.w};
            #pragma unroll
            for (int r2 = 0; r2 < 4; ++r2)
                #pragma unroll
                for (int c2 = 0; c2 < 4; ++c2)
                    acc[r2][c2] += aa[r2] * bb[c2];
        }
        __syncthreads();
    }
    float4 bb4 = *(const float4*)&bo[n0 + tn * 4];
    float badd[4] = {bb4.x, bb4.y, bb4.z, bb4.w};
    #pragma unroll
    for (int rr = 0; rr < 4; ++rr) {
        int r = m0 + tm * 4 + rr;
        float4 o;
        o.x = acc[rr][0] + badd[0];
        o.y = acc[rr][1] + badd[1];
        o.z = acc[rr][2] + badd[2];
        o.w = acc[rr][3] + badd[3];
        *(float4*)&y[r * 512 + n0 + tn * 4] = o;
    }
}

extern "C" void kernel_launch(void* const* d_in, const int* in_sizes, int n_in,
                              void* d_out, int out_size, void* d_ws, size_t ws_size,
                              hipStream_t stream)
{
    const float* x  = (const float*)d_in[0];
    const float* Wq = (const float*)d_in[1];
    const float* bq = (const float*)d_in[2];
    const float* Wk = (const float*)d_in[3];
    const float* bk = (const float*)d_in[4];
    const float* Wv = (const float*)d_in[5];
    const float* bv = (const float*)d_in[6];
    const float* W1 = (const float*)d_in[7];
    const float* b1 = (const float*)d_in[8];
    const float* W2 = (const float*)d_in[9];
    const float* b2 = (const float*)d_in[10];
    const float* Wo = (const float*)d_in[11];
    const float* bo = (const float*)d_in[12];
    float* y  = (float*)d_out;
    float* ws = (float*)d_ws;

    const size_t SEG = (size_t)BB * HH * CC * DH;  // 524288 floats
    float* qw  = ws;
    float* kw  = ws + SEG;
    float* vw  = ws + 2 * SEG;
    float* hqc = ws + 3 * SEG;
    float* hkw = ws + 4 * SEG;
    float* ow  = ws + 5 * SEG;   // needs 12.6 MB total workspace

    qkv_gemm<<<dim3(16, 24), 256, 0, stream>>>(x, Wq, bq, Wk, bk, Wv, bv, qw, kw, vw);
    h_lin<<<dim3(128, 2), 256, 0, stream>>>(qw, kw, W1, b1, hqc, hkw);
    attn_main<<<dim3(1024), 256, 0, stream>>>(qw, kw, vw, hqc, hkw, W1, W2, b2, ow);
    out_gemm<<<dim3(16, 8), 256, 0, stream>>>(ow, Wo, bo, y);
}

// Round 2
// 346.088 us; speedup vs baseline: 2.3327x; 2.3327x over previous
//
#include <hip/hip_runtime.h>
#include <math.h>

// Problem constants
#define BB 2
#define CC 512
#define DD 512
#define HH 8
#define DH 64
#define TI 8     // i-rows per attn2 block

typedef __attribute__((ext_vector_type(8))) short short8;      // 8 bf16 (4 VGPRs)
typedef __attribute__((ext_vector_type(16))) float floatx16;   // MFMA 32x32 acc

__device__ __forceinline__ float fast_rcp(float x) {
#if __has_builtin(__builtin_amdgcn_rcpf)
    return __builtin_amdgcn_rcpf(x);
#else
    return 1.0f / x;
#endif
}

__device__ __forceinline__ unsigned short f2bf(float f) {
    unsigned u = __float_as_uint(f);
    u += 0x7FFF + ((u >> 16) & 1);   // RNE
    return (unsigned short)(u >> 16);
}

// exact-erf gelu via Abramowitz-Stegun 7.1.26 (|eps| <= 1.5e-7)
__device__ __forceinline__ float gelu_exact(float h) {
    float u = h * 0.70710678118654752f;
    float a = fabsf(u);
    float t = fast_rcp(1.0f + 0.3275911f * a);
    float poly = t * (0.254829592f + t * (-0.284496736f + t * (1.421413741f +
                 t * (-1.453152027f + t * 1.061405429f))));
    float ex = __expf(-a * a);
    float erfa = 1.0f - poly * ex;
    float erfu = copysignf(erfa, u);
    return 0.5f * h * (1.0f + erfu);
}

// ---------------------------------------------------------------------------
// Kernel A: q,k,v = x @ {Wq,Wk,Wv} + bias, output layout [b][h][c][e]
// ---------------------------------------------------------------------------
__global__ __launch_bounds__(256) void qkv_gemm(
    const float* __restrict__ x,
    const float* __restrict__ Wq, const float* __restrict__ bq,
    const float* __restrict__ Wk, const float* __restrict__ bk,
    const float* __restrict__ Wv, const float* __restrict__ bv,
    float* __restrict__ qw, float* __restrict__ kw, float* __restrict__ vw)
{
    __shared__ float As[16][68];   // [kk][m]
    __shared__ float Bs[16][68];   // [kk][n]
    int t = threadIdx.x;
    int m0 = blockIdx.x * 64;
    int by = blockIdx.y;           // 0..23
    int mat = by >> 3;             // 0:q 1:k 2:v
    int n0 = (by & 7) * 64;        // within-matrix col base
    const float* W    = (mat == 0) ? Wq : (mat == 1) ? Wk : Wv;
    const float* bias = (mat == 0) ? bq : (mat == 1) ? bk : bv;
    float* out        = (mat == 0) ? qw : (mat == 1) ? kw : vw;

    int tm = t & 15, tn = t >> 4;
    int lm = t >> 2;
    int lk4 = (t & 3) * 4;
    float acc[4][4] = {};

    for (int k0 = 0; k0 < 512; k0 += 16) {
        float4 av  = *(const float4*)&x[(m0 + lm) * 512 + k0 + lk4];
        float4 bv4 = *(const float4*)&W[(k0 + (t >> 4)) * 512 + n0 + (t & 15) * 4];
        As[lk4 + 0][lm] = av.x; As[lk4 + 1][lm] = av.y;
        As[lk4 + 2][lm] = av.z; As[lk4 + 3][lm] = av.w;
        *(float4*)&Bs[t >> 4][(t & 15) * 4] = bv4;
        __syncthreads();
        #pragma unroll
        for (int kk = 0; kk < 16; ++kk) {
            float4 a4 = *(float4*)&As[kk][tm * 4];
            float4 b4 = *(float4*)&Bs[kk][tn * 4];
            float aa[4] = {a4.x, a4.y, a4.z, a4.w};
            float bb[4] = {b4.x, b4.y, b4.z, b4.w};
            #pragma unroll
            for (int r = 0; r < 4; ++r)
                #pragma unroll
                for (int c = 0; c < 4; ++c)
                    acc[r][c] += aa[r] * bb[c];
        }
        __syncthreads();
    }
    int h = n0 >> 6;
    int e0 = tn * 4;
    float4 bb4 = *(const float4*)&bias[n0 + e0];
    float badd[4] = {bb4.x, bb4.y, bb4.z, bb4.w};
    #pragma unroll
    for (int rr = 0; rr < 4; ++rr) {
        int r = m0 + tm * 4 + rr;
        int b = r >> 9, c = r & 511;
        float4 o;
        o.x = acc[rr][0] + badd[0];
        o.y = acc[rr][1] + badd[1];
        o.z = acc[rr][2] + badd[2];
        o.w = acc[rr][3] + badd[3];
        *(float4*)&out[((b * HH + h) * CC + c) * DH + e0] = o;
    }
}

// ---------------------------------------------------------------------------
// Kernel A2: hqc = b1 + q @ W1[0:64]
// ---------------------------------------------------------------------------
__global__ __launch_bounds__(256) void h_lin_q(
    const float* __restrict__ q,
    const float* __restrict__ W1, const float* __restrict__ b1,
    float* __restrict__ hqc)
{
    __shared__ float ws[64][68];   // W1q[d][e]
    __shared__ float rsT[64][68];  // q transposed [d][row]
    int t = threadIdx.x;
    int r0 = blockIdx.x * 64;

    for (int idx = t; idx < 4096; idx += 256) {
        int d = idx >> 6, e = idx & 63;
        ws[d][e] = W1[d * 64 + e];
    }
    {
        int j = t >> 2;
        int d0 = (t & 3) * 16;
        #pragma unroll
        for (int c = 0; c < 16; c += 4) {
            float4 vv = *(const float4*)&q[(r0 + j) * 64 + d0 + c];
            rsT[d0 + c + 0][j] = vv.x; rsT[d0 + c + 1][j] = vv.y;
            rsT[d0 + c + 2][j] = vv.z; rsT[d0 + c + 3][j] = vv.w;
        }
    }
    __syncthreads();
    int j = t & 63;
    int e0 = (t >> 6) * 16;
    float acc[16] = {};
    for (int d = 0; d < 64; ++d) {
        float kv = rsT[d][j];
        #pragma unroll
        for (int c = 0; c < 16; ++c) acc[c] += kv * ws[d][e0 + c];
    }
    #pragma unroll
    for (int c = 0; c < 16; ++c) acc[c] += b1[e0 + c];
    #pragma unroll
    for (int c = 0; c < 16; c += 4) {
        float4 o = {acc[c], acc[c + 1], acc[c + 2], acc[c + 3]};
        *(float4*)&hqc[(r0 + j) * 64 + e0 + c] = o;
    }
}

// ---------------------------------------------------------------------------
// Kernel B (attn2): MFMA second-order core.
// Per (b,h, 8-i tile): for each i, GEMM C[e,j] = A_i[e,d] @ K^T[d,j] where
// A_i[e,d] = q_i[d]*W1i[d,e] + W1k[d,e]  (hk absorbed into the contraction).
// Epilogue: h = C + (hq_i[e]+b1[e]); gelu; dot W2 over e via in-lane regs +
// shfl_xor(32). Then softmax + PV as before.
// ---------------------------------------------------------------------------
__global__ __launch_bounds__(256, 2) void attn2(
    const float* __restrict__ qw, const float* __restrict__ kw,
    const float* __restrict__ vw, const float* __restrict__ hqc,
    const float* __restrict__ W1, const float* __restrict__ W2,
    const float* __restrict__ b2p,
    float* __restrict__ ow)
{
    __shared__ float2 w1x[64][64];          // (W1i, W1k)[d][e]   32 KB
    __shared__ unsigned short Alds[64][64]; // A_i bf16, xor-swizzled, 8 KB
    __shared__ float sc[TI][512];           // scores              16 KB

    int t = threadIdx.x;
    int lane = t & 63;
    int w = t >> 6;          // wave 0..3 -> owns j in [w*128, w*128+128)
    int h = lane >> 5;       // lane half
    int col = lane & 31;

    int bh = blockIdx.x >> 6;            // 0..15
    int i0 = (blockIdx.x & 63) * TI;

    const float* qb  = qw  + ((size_t)bh * CC + i0) * DH;
    const float* hb  = hqc + ((size_t)bh * CC + i0) * DH;
    const float* kb  = kw  + (size_t)bh * CC * DH;
    const float* vb  = vw  + (size_t)bh * CC * DH;

    // one-time: stage interleaved W1i/W1k
    for (int idx = t; idx < 4096; idx += 256) {
        int d = idx >> 6, e = idx & 63;
        w1x[d][e] = make_float2(W1[(128 + d) * 64 + e], W1[(64 + d) * 64 + e]);
    }

    // one-time: B fragments (k as bf16), i-invariant, held in registers.
    // B[k=h*8+b][col] for K-step kk => k[j][kk*16 + h*8 + b]
    short8 bfrag[4][4];
    for (int n = 0; n < 4; ++n) {
        int j = w * 128 + n * 32 + col;
        const float* kr = kb + (size_t)j * 64;
        #pragma unroll
        for (int kk = 0; kk < 4; ++kk) {
            int d = kk * 16 + h * 8;
            float4 k0 = *(const float4*)(kr + d);
            float4 k1 = *(const float4*)(kr + d + 4);
            short8 f;
            f[0] = (short)f2bf(k0.x); f[1] = (short)f2bf(k0.y);
            f[2] = (short)f2bf(k0.z); f[3] = (short)f2bf(k0.w);
            f[4] = (short)f2bf(k1.x); f[5] = (short)f2bf(k1.y);
            f[6] = (short)f2bf(k1.z); f[7] = (short)f2bf(k1.w);
            bfrag[n][kk] = f;
        }
    }

    // one-time: W2 per-lane fragments, e = m*32 + g*8 + h*4 + r2
    float4 w2r[2][4];
    #pragma unroll
    for (int m = 0; m < 2; ++m)
        #pragma unroll
        for (int g = 0; g < 4; ++g)
            w2r[m][g] = *(const float4*)&W2[m * 32 + g * 8 + h * 4];

    __syncthreads();   // w1x ready

    for (int ii = 0; ii < TI; ++ii) {
        // --- produce A_i into LDS (each lane: 2 groups of 8 d's, one e) ---
        {
            int e = lane;
            int sw = e & 7;
            #pragma unroll
            for (int gg = 0; gg < 2; ++gg) {
                int g8 = w * 2 + gg;          // d-group 0..7
                const float* qr = qb + ii * 64 + g8 * 8;
                float4 q0 = *(const float4*)qr;
                float4 q1 = *(const float4*)(qr + 4);
                float qv[8] = {q0.x, q0.y, q0.z, q0.w, q1.x, q1.y, q1.z, q1.w};
                unsigned int pk[4];
                #pragma unroll
                for (int p2 = 0; p2 < 4; ++p2) {
                    float2 wv0 = w1x[g8 * 8 + 2 * p2 + 0][e];
                    float2 wv1 = w1x[g8 * 8 + 2 * p2 + 1][e];
                    float a0 = fmaf(qv[2 * p2 + 0], wv0.x, wv0.y);
                    float a1 = fmaf(qv[2 * p2 + 1], wv1.x, wv1.y);
                    pk[p2] = (unsigned)f2bf(a0) | ((unsigned)f2bf(a1) << 16);
                }
                *(uint4*)&Alds[e][(g8 ^ sw) * 8] = make_uint4(pk[0], pk[1], pk[2], pk[3]);
            }
        }
        __syncthreads();

        // --- load A fragments (conflict-spread b128 reads) ---
        short8 afrag[2][4];
        #pragma unroll
        for (int m = 0; m < 2; ++m) {
            int e = m * 32 + col;
            int sw = e & 7;
            #pragma unroll
            for (int kk = 0; kk < 4; ++kk) {
                int g8 = kk * 2 + h;
                afrag[m][kk] = *(short8*)&Alds[e][(g8 ^ sw) * 8];
            }
        }
        // cs = hq_i + b1 fragments from global (L1-hot row)
        float4 csr[2][4];
        #pragma unroll
        for (int m = 0; m < 2; ++m)
            #pragma unroll
            for (int g = 0; g < 4; ++g)
                csr[m][g] = *(const float4*)&hb[ii * 64 + m * 32 + g * 8 + h * 4];

        // --- per N-tile: 8 MFMAs + gelu/W2 epilogue ---
        #pragma unroll
        for (int n = 0; n < 4; ++n) {
            floatx16 acc[2];
            acc[0] = {0.0f,0.0f,0.0f,0.0f,0.0f,0.0f,0.0f,0.0f,
                      0.0f,0.0f,0.0f,0.0f,0.0f,0.0f,0.0f,0.0f};
            acc[1] = acc[0];
            #pragma unroll
            for (int kk = 0; kk < 4; ++kk) {
                acc[0] = __builtin_amdgcn_mfma_f32_32x32x16_bf16(
                             afrag[0][kk], bfrag[n][kk], acc[0], 0, 0, 0);
                acc[1] = __builtin_amdgcn_mfma_f32_32x32x16_bf16(
                             afrag[1][kk], bfrag[n][kk], acc[1], 0, 0, 0);
            }
            float p = 0.0f;
            #pragma unroll
            for (int m = 0; m < 2; ++m) {
                #pragma unroll
                for (int g = 0; g < 4; ++g) {
                    float4 c4 = csr[m][g];
                    float4 w4 = w2r[m][g];
                    float ccv[4] = {c4.x, c4.y, c4.z, c4.w};
                    float wwv[4] = {w4.x, w4.y, w4.z, w4.w};
                    #pragma unroll
                    for (int r2 = 0; r2 < 4; ++r2) {
                        float hh = acc[m][g * 4 + r2] + ccv[r2];
                        p = fmaf(gelu_exact(hh), wwv[r2], p);
                    }
                }
            }
            p += __shfl_xor(p, 32);
            if (h == 0) sc[ii][w * 128 + n * 32 + col] = p;
        }
        __syncthreads();
    }

    // --- softmax over j per i-row; scores = (raw + b2)/8 ---
    float b2v = b2p[0];
    for (int iirow = w; iirow < TI; iirow += 4) {
        float xv[8];
        float m = -1e30f;
        #pragma unroll
        for (int c = 0; c < 8; ++c) {
            xv[c] = (sc[iirow][c * 64 + lane] + b2v) * 0.125f;
            m = fmaxf(m, xv[c]);
        }
        #pragma unroll
        for (int o = 1; o < 64; o <<= 1) m = fmaxf(m, __shfl_xor(m, o));
        float s = 0.0f;
        #pragma unroll
        for (int c = 0; c < 8; ++c) { xv[c] = __expf(xv[c] - m); s += xv[c]; }
        #pragma unroll
        for (int o = 1; o < 64; o <<= 1) s += __shfl_xor(s, o);
        float r = fast_rcp(s);
        #pragma unroll
        for (int c = 0; c < 8; ++c) sc[iirow][c * 64 + lane] = xv[c] * r;
    }
    __syncthreads();

    // --- out[i][e] = sum_j attn[i][j] * v[j][e] ---
    {
        int e = lane;
        int g = w;
        int ia = 2 * g, ib = 2 * g + 1;
        float a0 = 0.0f, a1 = 0.0f;
        #pragma unroll 8
        for (int j = 0; j < 512; ++j) {
            float vvl = vb[j * 64 + e];
            a0 += sc[ia][j] * vvl;
            a1 += sc[ib][j] * vvl;
        }
        ow[((size_t)bh * CC + i0 + ia) * DH + e] = a0;
        ow[((size_t)bh * CC + i0 + ib) * DH + e] = a1;
    }
}

// ---------------------------------------------------------------------------
// Kernel D: y = reshape(attn_out to (B*C, D)) @ Wo + bo
// ---------------------------------------------------------------------------
__global__ __launch_bounds__(256) void out_gemm(
    const float* __restrict__ ow, const float* __restrict__ Wo,
    const float* __restrict__ bo, float* __restrict__ y)
{
    __shared__ float As[16][68];
    __shared__ float Bs[16][68];
    int t = threadIdx.x;
    int m0 = blockIdx.x * 64;
    int n0 = blockIdx.y * 64;
    int tm = t & 15, tn = t >> 4;
    int lm = t >> 2;
    int lk4 = (t & 3) * 4;
    float acc[4][4] = {};

    for (int k0 = 0; k0 < 512; k0 += 16) {
        int r = m0 + lm;
        int b = r >> 9, c = r & 511;
        int kk = k0 + lk4;
        int hh = kk >> 6, e = kk & 63;
        float4 av  = *(const float4*)&ow[((b * HH + hh) * CC + c) * DH + e];
        float4 bv4 = *(const float4*)&Wo[(k0 + (t >> 4)) * 512 + n0 + (t & 15) * 4];
        As[lk4 + 0][lm] = av.x; As[lk4 + 1][lm] = av.y;
        As[lk4 + 2][lm] = av.z; As[lk4 + 3][lm] = av.w;
        *(float4*)&Bs[t >> 4][(t & 15) * 4] = bv4;
        __syncthreads();
        #pragma unroll
        for (int kk2 = 0; kk2 < 16; ++kk2) {
            float4 a4 = *(float4*)&As[kk2][tm * 4];
            float4 b4 = *(float4*)&Bs[kk2][tn * 4];
            float aa[4] = {a4.x, a4.y, a4.z, a4.w};
            float bb[4] = {b4.x, b4.y, b4.z, b4.w};
            #pragma unroll
            for (int r2 = 0; r2 < 4; ++r2)
                #pragma unroll
                for (int c2 = 0; c2 < 4; ++c2)
                    acc[r2][c2] += aa[r2] * bb[c2];
        }
        __syncthreads();
    }
    float4 bb4 = *(const float4*)&bo[n0 + tn * 4];
    float badd[4] = {bb4.x, bb4.y, bb4.z, bb4.w};
    #pragma unroll
    for (int rr = 0; rr < 4; ++rr) {
        int r = m0 + tm * 4 + rr;
        float4 o;
        o.x = acc[rr][0] + badd[0];
        o.y = acc[rr][1] + badd[1];
        o.z = acc[rr][2] + badd[2];
        o.w = acc[rr][3] + badd[3];
        *(float4*)&y[r * 512 + n0 + tn * 4] = o;
    }
}

extern "C" void kernel_launch(void* const* d_in, const int* in_sizes, int n_in,
                              void* d_out, int out_size, void* d_ws, size_t ws_size,
                              hipStream_t stream)
{
    const float* x  = (const float*)d_in[0];
    const float* Wq = (const float*)d_in[1];
    const float* bq = (const float*)d_in[2];
    const float* Wk = (const float*)d_in[3];
    const float* bk = (const float*)d_in[4];
    const float* Wv = (const float*)d_in[5];
    const float* bv = (const float*)d_in[6];
    const float* W1 = (const float*)d_in[7];
    const float* b1 = (const float*)d_in[8];
    const float* W2 = (const float*)d_in[9];
    const float* b2 = (const float*)d_in[10];
    const float* Wo = (const float*)d_in[11];
    const float* bo = (const float*)d_in[12];
    float* y  = (float*)d_out;
    float* ws = (float*)d_ws;

    const size_t SEG = (size_t)BB * HH * CC * DH;  // 524288 floats
    float* qw  = ws;
    float* kw  = ws + SEG;
    float* vw  = ws + 2 * SEG;
    float* hqc = ws + 3 * SEG;
    float* ow  = ws + 4 * SEG;   // 10.5 MB total workspace

    qkv_gemm<<<dim3(16, 24), 256, 0, stream>>>(x, Wq, bq, Wk, bk, Wv, bv, qw, kw, vw);
    h_lin_q<<<dim3(128), 256, 0, stream>>>(qw, W1, b1, hqc);
    attn2<<<dim3(1024), 256, 0, stream>>>(qw, kw, vw, hqc, W1, W2, b2, ow);
    out_gemm<<<dim3(16, 8), 256, 0, stream>>>(ow, Wo, bo, y);
}

// Round 3
// 292.593 us; speedup vs baseline: 2.7591x; 1.1828x over previous
//
#include <hip/hip_runtime.h>
#include <math.h>

// Problem constants
#define BB 2
#define CC 512
#define DD 512
#define HH 8
#define DH 64
#define TI 8     // i-rows per attn2 block

typedef __attribute__((ext_vector_type(8))) short short8;      // 8 bf16 (4 VGPRs)
typedef __attribute__((ext_vector_type(16))) float floatx16;   // MFMA 32x32 acc

__device__ __forceinline__ float fast_rcp(float x) {
#if __has_builtin(__builtin_amdgcn_rcpf)
    return __builtin_amdgcn_rcpf(x);
#else
    return 1.0f / x;
#endif
}

__device__ __forceinline__ unsigned short f2bf(float f) {
    unsigned u = __float_as_uint(f);
    u += 0x7FFF + ((u >> 16) & 1);   // RNE
    return (unsigned short)(u >> 16);
}

// gelu via cubic-logistic normal CDF (Bowling): Phi(h) ~ sigma(1.5976h+0.07056h^3)
// |Phi err| <= 1.4e-4; with |h| <~ 1 here, end-to-end effect ~1e-5. 9 VALU instrs.
__device__ __forceinline__ float gelu_s(float h) {
    float s = h * h;
    float u = h * fmaf(s, 0.07056f, 1.5976f);
    float sig = fast_rcp(1.0f + __expf(-u));
    return h * sig;
}

// ---------------------------------------------------------------------------
// Kernel A: q,k,v = x @ {Wq,Wk,Wv} + bias, output layout [b][h][c][e].
// For the q blocks (mat==0) additionally computes hqc = b1 + q @ W1[0:64]
// (the block's 64 rows x 64 head-dims are exactly the contraction needed).
// ---------------------------------------------------------------------------
__global__ __launch_bounds__(256) void qkv_gemm(
    const float* __restrict__ x,
    const float* __restrict__ Wq, const float* __restrict__ bq,
    const float* __restrict__ Wk, const float* __restrict__ bk,
    const float* __restrict__ Wv, const float* __restrict__ bv,
    const float* __restrict__ W1, const float* __restrict__ b1,
    float* __restrict__ qw, float* __restrict__ kw, float* __restrict__ vw,
    float* __restrict__ hqc)
{
    __shared__ float As[16][68];   // [kk][m]
    __shared__ float Bs[16][68];   // [kk][n]
    __shared__ float qs2[64][68];  // q tile transposed [e][row] (mat==0 only)
    __shared__ float ws2[64][68];  // W1q [d][e]
    int t = threadIdx.x;
    int m0 = blockIdx.x * 64;
    int by = blockIdx.y;           // 0..23
    int mat = by >> 3;             // 0:q 1:k 2:v
    int n0 = (by & 7) * 64;        // within-matrix col base
    const float* W    = (mat == 0) ? Wq : (mat == 1) ? Wk : Wv;
    const float* bias = (mat == 0) ? bq : (mat == 1) ? bk : bv;
    float* out        = (mat == 0) ? qw : (mat == 1) ? kw : vw;

    int tm = t & 15, tn = t >> 4;
    int lm = t >> 2;
    int lk4 = (t & 3) * 4;
    float acc[4][4] = {};

    for (int k0 = 0; k0 < 512; k0 += 16) {
        float4 av  = *(const float4*)&x[(m0 + lm) * 512 + k0 + lk4];
        float4 bv4 = *(const float4*)&W[(k0 + (t >> 4)) * 512 + n0 + (t & 15) * 4];
        As[lk4 + 0][lm] = av.x; As[lk4 + 1][lm] = av.y;
        As[lk4 + 2][lm] = av.z; As[lk4 + 3][lm] = av.w;
        *(float4*)&Bs[t >> 4][(t & 15) * 4] = bv4;
        __syncthreads();
        #pragma unroll
        for (int kk = 0; kk < 16; ++kk) {
            float4 a4 = *(float4*)&As[kk][tm * 4];
            float4 b4 = *(float4*)&Bs[kk][tn * 4];
            float aa[4] = {a4.x, a4.y, a4.z, a4.w};
            float bb[4] = {b4.x, b4.y, b4.z, b4.w};
            #pragma unroll
            for (int r = 0; r < 4; ++r)
                #pragma unroll
                for (int c = 0; c < 4; ++c)
                    acc[r][c] += aa[r] * bb[c];
        }
        __syncthreads();
    }
    int h = n0 >> 6;
    int e0 = tn * 4;
    float4 bb4 = *(const float4*)&bias[n0 + e0];
    float badd[4] = {bb4.x, bb4.y, bb4.z, bb4.w};
    #pragma unroll
    for (int rr = 0; rr < 4; ++rr) {
        int r = m0 + tm * 4 + rr;
        int b = r >> 9, c = r & 511;
        float4 o;
        o.x = acc[rr][0] + badd[0];
        o.y = acc[rr][1] + badd[1];
        o.z = acc[rr][2] + badd[2];
        o.w = acc[rr][3] + badd[3];
        *(float4*)&out[((b * HH + h) * CC + c) * DH + e0] = o;
    }

    if (mat == 0) {
        // fused hqc = b1 + q_tile @ W1q
        #pragma unroll
        for (int rr = 0; rr < 4; ++rr)
            #pragma unroll
            for (int cc = 0; cc < 4; ++cc)
                qs2[tn * 4 + cc][tm * 4 + rr] = acc[rr][cc] + badd[cc];
        for (int idx = t; idx < 4096; idx += 256)
            ws2[idx >> 6][idx & 63] = W1[idx];
        __syncthreads();
        int j = t & 63;              // local row
        int ee0 = (t >> 6) * 16;
        float acc2[16] = {};
        for (int d = 0; d < 64; ++d) {
            float qv = qs2[d][j];
            #pragma unroll
            for (int c = 0; c < 16; ++c) acc2[c] += qv * ws2[d][ee0 + c];
        }
        #pragma unroll
        for (int c = 0; c < 16; ++c) acc2[c] += b1[ee0 + c];
        int r = m0 + j;
        int b = r >> 9, c = r & 511;
        #pragma unroll
        for (int cc = 0; cc < 16; cc += 4) {
            float4 o = {acc2[cc], acc2[cc + 1], acc2[cc + 2], acc2[cc + 3]};
            *(float4*)&hqc[((b * HH + h) * CC + c) * DH + ee0 + cc] = o;
        }
    }
}

// ---------------------------------------------------------------------------
// Kernel B (attn2): MFMA second-order core.
// Per (b,h, 8-i tile): for each i, GEMM C[e,j] = A_i[e,d] @ K^T[d,j] where
// A_i[e,d] = q_i[d]*W1i[d,e] + W1k[d,e]  (hk absorbed into the contraction)
// plus a 5th K-step with A[e][64]=hq_i[e]+b1[e], B[64][j]=1 (cs absorbed).
// Epilogue: gelu(C) dot W2 over e (in-lane regs + shfl_xor(32)), softmax, PV.
// ---------------------------------------------------------------------------
__global__ __launch_bounds__(256, 2) void attn2(
    const float* __restrict__ qw, const float* __restrict__ kw,
    const float* __restrict__ vw, const float* __restrict__ hqc,
    const float* __restrict__ W1, const float* __restrict__ W2,
    const float* __restrict__ b2p,
    float* __restrict__ ow)
{
    __shared__ float2 w1x[64][64];           // (W1i, W1k)[d][e]   32 KB
    __shared__ unsigned short Alds[64][128]; // A_i bf16, 16 blocks/row, 16 KB
    __shared__ float sc[TI][512];            // scores             16 KB

    int t = threadIdx.x;
    int lane = t & 63;
    int w = t >> 6;          // wave 0..3 -> owns j in [w*128, w*128+128)
    int h = lane >> 5;       // lane half
    int col = lane & 31;

    int bh = blockIdx.x >> 6;            // 0..15
    int i0 = (blockIdx.x & 63) * TI;

    const float* qb  = qw  + ((size_t)bh * CC + i0) * DH;
    const float* hb  = hqc + ((size_t)bh * CC + i0) * DH;
    const float* kb  = kw  + (size_t)bh * CC * DH;
    const float* vb  = vw  + (size_t)bh * CC * DH;

    // one-time: stage interleaved W1i/W1k
    for (int idx = t; idx < 4096; idx += 256) {
        int d = idx >> 6, e = idx & 63;
        w1x[d][e] = make_float2(W1[(128 + d) * 64 + e], W1[(64 + d) * 64 + e]);
    }

    // one-time: B fragments (k as bf16), i-invariant, held in registers.
    short8 bfrag[4][4];
    for (int n = 0; n < 4; ++n) {
        int j = w * 128 + n * 32 + col;
        const float* kr = kb + (size_t)j * 64;
        #pragma unroll
        for (int kk = 0; kk < 4; ++kk) {
            int d = kk * 16 + h * 8;
            float4 k0 = *(const float4*)(kr + d);
            float4 k1 = *(const float4*)(kr + d + 4);
            short8 f;
            f[0] = (short)f2bf(k0.x); f[1] = (short)f2bf(k0.y);
            f[2] = (short)f2bf(k0.z); f[3] = (short)f2bf(k0.w);
            f[4] = (short)f2bf(k1.x); f[5] = (short)f2bf(k1.y);
            f[6] = (short)f2bf(k1.z); f[7] = (short)f2bf(k1.w);
            bfrag[n][kk] = f;
        }
    }
    // 5th K-step B fragment: B[64][j]=1, B[65..79][j]=0 -> lane h==0, b==0
    short8 breg5 = {0, 0, 0, 0, 0, 0, 0, 0};
    if (h == 0) breg5[0] = (short)0x3F80;   // bf16(1.0)

    // one-time: W2 per-lane fragments, e = m*32 + g*8 + h*4 + r2
    float4 w2r[2][4];
    #pragma unroll
    for (int m = 0; m < 2; ++m)
        #pragma unroll
        for (int g = 0; g < 4; ++g)
            w2r[m][g] = *(const float4*)&W2[m * 32 + g * 8 + h * 4];

    __syncthreads();   // w1x ready

    for (int ii = 0; ii < TI; ++ii) {
        // --- produce A_i into LDS (each lane: 2 d-groups of 8, one e) ---
        {
            int e = lane;
            int sw = e & 7;
            #pragma unroll
            for (int gg = 0; gg < 2; ++gg) {
                int g8 = w * 2 + gg;          // d-group 0..7
                const float* qr = qb + ii * 64 + g8 * 8;
                float4 q0 = *(const float4*)qr;
                float4 q1 = *(const float4*)(qr + 4);
                float qv[8] = {q0.x, q0.y, q0.z, q0.w, q1.x, q1.y, q1.z, q1.w};
                unsigned int pk[4];
                #pragma unroll
                for (int p2 = 0; p2 < 4; ++p2) {
                    float2 wv0 = w1x[g8 * 8 + 2 * p2 + 0][e];
                    float2 wv1 = w1x[g8 * 8 + 2 * p2 + 1][e];
                    float a0 = fmaf(qv[2 * p2 + 0], wv0.x, wv0.y);
                    float a1 = fmaf(qv[2 * p2 + 1], wv1.x, wv1.y);
                    pk[p2] = (unsigned)f2bf(a0) | ((unsigned)f2bf(a1) << 16);
                }
                *(uint4*)&Alds[e][(g8 ^ sw) * 8] = make_uint4(pk[0], pk[1], pk[2], pk[3]);
            }
            // K-extension blocks: block8 = (cs,0,...), block9 = zeros
            if (w == 0) {
                float csv = hb[ii * 64 + e];
                *(uint4*)&Alds[e][(8 ^ sw) * 8] =
                    make_uint4((unsigned)f2bf(csv), 0, 0, 0);
            } else if (w == 1) {
                *(uint4*)&Alds[e][(9 ^ sw) * 8] = make_uint4(0, 0, 0, 0);
            }
        }
        __syncthreads();

        // --- load A fragments (5 K-steps) ---
        short8 afrag[2][5];
        #pragma unroll
        for (int m = 0; m < 2; ++m) {
            int e = m * 32 + col;
            int sw = e & 7;
            #pragma unroll
            for (int kk = 0; kk < 5; ++kk) {
                int g8 = kk * 2 + h;          // kk=4 -> 8+h (cs extension)
                afrag[m][kk] = *(short8*)&Alds[e][(g8 ^ sw) * 8];
            }
        }

        // --- per N-tile: 10 MFMAs + gelu/W2 epilogue ---
        #pragma unroll
        for (int n = 0; n < 4; ++n) {
            floatx16 acc[2];
            acc[0] = {0.0f,0.0f,0.0f,0.0f,0.0f,0.0f,0.0f,0.0f,
                      0.0f,0.0f,0.0f,0.0f,0.0f,0.0f,0.0f,0.0f};
            acc[1] = acc[0];
            #pragma unroll
            for (int kk = 0; kk < 4; ++kk) {
                acc[0] = __builtin_amdgcn_mfma_f32_32x32x16_bf16(
                             afrag[0][kk], bfrag[n][kk], acc[0], 0, 0, 0);
                acc[1] = __builtin_amdgcn_mfma_f32_32x32x16_bf16(
                             afrag[1][kk], bfrag[n][kk], acc[1], 0, 0, 0);
            }
            acc[0] = __builtin_amdgcn_mfma_f32_32x32x16_bf16(
                         afrag[0][4], breg5, acc[0], 0, 0, 0);
            acc[1] = __builtin_amdgcn_mfma_f32_32x32x16_bf16(
                         afrag[1][4], breg5, acc[1], 0, 0, 0);
            float p = 0.0f;
            #pragma unroll
            for (int m = 0; m < 2; ++m) {
                #pragma unroll
                for (int g = 0; g < 4; ++g) {
                    float4 w4 = w2r[m][g];
                    float wwv[4] = {w4.x, w4.y, w4.z, w4.w};
                    #pragma unroll
                    for (int r2 = 0; r2 < 4; ++r2)
                        p = fmaf(gelu_s(acc[m][g * 4 + r2]), wwv[r2], p);
                }
            }
            p += __shfl_xor(p, 32);
            if (h == 0) sc[ii][w * 128 + n * 32 + col] = p;
        }
        __syncthreads();
    }

    // --- softmax over j per i-row; scores = (raw + b2)/8 ---
    float b2v = b2p[0];
    for (int iirow = w; iirow < TI; iirow += 4) {
        float xv[8];
        float m = -1e30f;
        #pragma unroll
        for (int c = 0; c < 8; ++c) {
            xv[c] = (sc[iirow][c * 64 + lane] + b2v) * 0.125f;
            m = fmaxf(m, xv[c]);
        }
        #pragma unroll
        for (int o = 1; o < 64; o <<= 1) m = fmaxf(m, __shfl_xor(m, o));
        float s = 0.0f;
        #pragma unroll
        for (int c = 0; c < 8; ++c) { xv[c] = __expf(xv[c] - m); s += xv[c]; }
        #pragma unroll
        for (int o = 1; o < 64; o <<= 1) s += __shfl_xor(s, o);
        float r = fast_rcp(s);
        #pragma unroll
        for (int c = 0; c < 8; ++c) sc[iirow][c * 64 + lane] = xv[c] * r;
    }
    __syncthreads();

    // --- out[i][e] = sum_j attn[i][j] * v[j][e] ---
    {
        int e = lane;
        int g = w;
        int ia = 2 * g, ib = 2 * g + 1;
        float a0 = 0.0f, a1 = 0.0f;
        #pragma unroll 8
        for (int j = 0; j < 512; ++j) {
            float vvl = vb[j * 64 + e];
            a0 += sc[ia][j] * vvl;
            a1 += sc[ib][j] * vvl;
        }
        ow[((size_t)bh * CC + i0 + ia) * DH + e] = a0;
        ow[((size_t)bh * CC + i0 + ib) * DH + e] = a1;
    }
}

// ---------------------------------------------------------------------------
// Kernel D: y = reshape(attn_out to (B*C, D)) @ Wo + bo
// ---------------------------------------------------------------------------
__global__ __launch_bounds__(256) void out_gemm(
    const float* __restrict__ ow, const float* __restrict__ Wo,
    const float* __restrict__ bo, float* __restrict__ y)
{
    __shared__ float As[16][68];
    __shared__ float Bs[16][68];
    int t = threadIdx.x;
    int m0 = blockIdx.x * 64;
    int n0 = blockIdx.y * 64;
    int tm = t & 15, tn = t >> 4;
    int lm = t >> 2;
    int lk4 = (t & 3) * 4;
    float acc[4][4] = {};

    for (int k0 = 0; k0 < 512; k0 += 16) {
        int r = m0 + lm;
        int b = r >> 9, c = r & 511;
        int kk = k0 + lk4;
        int hh = kk >> 6, e = kk & 63;
        float4 av  = *(const float4*)&ow[((b * HH + hh) * CC + c) * DH + e];
        float4 bv4 = *(const float4*)&Wo[(k0 + (t >> 4)) * 512 + n0 + (t & 15) * 4];
        As[lk4 + 0][lm] = av.x; As[lk4 + 1][lm] = av.y;
        As[lk4 + 2][lm] = av.z; As[lk4 + 3][lm] = av.w;
        *(float4*)&Bs[t >> 4][(t & 15) * 4] = bv4;
        __syncthreads();
        #pragma unroll
        for (int kk2 = 0; kk2 < 16; ++kk2) {
            float4 a4 = *(float4*)&As[kk2][tm * 4];
            float4 b4 = *(float4*)&Bs[kk2][tn * 4];
            float aa[4] = {a4.x, a4.y, a4.z, a4.w};
            float bb[4] = {b4.x, b4.y, b4.z, b4.w};
            #pragma unroll
            for (int r2 = 0; r2 < 4; ++r2)
                #pragma unroll
                for (int c2 = 0; c2 < 4; ++c2)
                    acc[r2][c2] += aa[r2] * bb[c2];
        }
        __syncthreads();
    }
    float4 bb4 = *(const float4*)&bo[n0 + tn * 4];
    float badd[4] = {bb4.x, bb4.y, bb4.z, bb4.w};
    #pragma unroll
    for (int rr = 0; rr < 4; ++rr) {
        int r = m0 + tm * 4 + rr;
        float4 o;
        o.x = acc[rr][0] + badd[0];
        o.y = acc[rr][1] + badd[1];
        o.z = acc[rr][2] + badd[2];
        o.w = acc[rr][3] + badd[3];
        *(float4*)&y[r * 512 + n0 + tn * 4] = o;
    }
}

extern "C" void kernel_launch(void* const* d_in, const int* in_sizes, int n_in,
                              void* d_out, int out_size, void* d_ws, size_t ws_size,
                              hipStream_t stream)
{
    const float* x  = (const float*)d_in[0];
    const float* Wq = (const float*)d_in[1];
    const float* bq = (const float*)d_in[2];
    const float* Wk = (const float*)d_in[3];
    const float* bk = (const float*)d_in[4];
    const float* Wv = (const float*)d_in[5];
    const float* bv = (const float*)d_in[6];
    const float* W1 = (const float*)d_in[7];
    const float* b1 = (const float*)d_in[8];
    const float* W2 = (const float*)d_in[9];
    const float* b2 = (const float*)d_in[10];
    const float* Wo = (const float*)d_in[11];
    const float* bo = (const float*)d_in[12];
    float* y  = (float*)d_out;
    float* ws = (float*)d_ws;

    const size_t SEG = (size_t)BB * HH * CC * DH;  // 524288 floats
    float* qw  = ws;
    float* kw  = ws + SEG;
    float* vw  = ws + 2 * SEG;
    float* hqc = ws + 3 * SEG;
    float* ow  = ws + 4 * SEG;   // 10.5 MB total workspace

    qkv_gemm<<<dim3(16, 24), 256, 0, stream>>>(x, Wq, bq, Wk, bk, Wv, bv, W1, b1,
                                               qw, kw, vw, hqc);
    attn2<<<dim3(1024), 256, 0, stream>>>(qw, kw, vw, hqc, W1, W2, b2, ow);
    out_gemm<<<dim3(16, 8), 256, 0, stream>>>(ow, Wo, bo, y);
}